// Round 1
// baseline (883.514 us; speedup 1.0000x reference)
//
#include <hip/hip_runtime.h>

// Batched ADMM QP solver. B=1024 batches, one workgroup per batch.
// Per batch: build K = Q + sigma*I + rho*At*A (Amat=[A;G], 80x64), invert via
// Gauss-Jordan (SPD, no pivoting needed), then 800 iterations of
//   t = sigma*x - p + At*(z - y)   (rho = 1)
//   x = Kinv * t
//   s = A*x + y;  z = clip(s,l,u);  y = s - z;  w = 2z - s
// Matrices are register-resident (per-lane row fragments); vectors in LDS.

#define NX    64
#define NEQ   16
#define NIN   64
#define M     80
#define ITERS 800
#define SIGMA 1e-6f

#define AUGW  132   // augmented [K|I] row stride (64+64+4 pad), 33 cols per quad-lane
#define AMW   68    // staged Amat row stride (16B-aligned rows, odd bank phase)

__global__ __launch_bounds__(256, 4)
void admm_qp_kernel(const float* __restrict__ Q, const float* __restrict__ p,
                    const float* __restrict__ A, const float* __restrict__ bvec,
                    const float* __restrict__ G, const float* __restrict__ h,
                    float* __restrict__ out)
{
    __shared__ float sm[64 * AUGW + 64 + 80 + 80 + 64 + 64 + 80 + 80];
    float* aug = sm;                  // setup scratch: amat stage, then augmented [K|I]
    float* pL  = sm + 64 * AUGW;      // 64
    float* lL  = pL + 64;             // 80
    float* uL  = lL + 80;             // 80
    float* xL  = uL + 80;             // 64
    float* tL  = xL + 64;             // 64
    float* yL  = tL + 64;             // 80
    float* wL  = yL + 80;             // 80

    const int b = blockIdx.x;
    const int t = threadIdx.x;
    const int q = t & 3;              // quad lane
    const int i = t >> 2;             // output row 0..63

    const float* Ab = A + (size_t)b * NEQ * NX;
    const float* Gb = G + (size_t)b * NIN * NX;
    const float* Qb = Q + (size_t)b * NX * NX;

    // ---- stage p, l, u; init state x=y=w=0 ----
    if (t < 64) { pL[t] = p[(size_t)b * 64 + t]; xL[t] = 0.f; }
    if (t < 80) {
        float lo, up;
        if (t < 16) { lo = up = bvec[(size_t)b * 16 + t]; }
        else        { lo = -1e8f; up = h[(size_t)b * 64 + (t - 16)]; }
        lL[t] = lo; uL[t] = up; yL[t] = 0.f; wL[t] = 0.f;
    }

    // ---- stage Amat rows into LDS (row r: r<16 -> A, else G) ----
    float* amatL = sm;
    for (int e = t; e < M * 16; e += 256) {
        int row = e >> 4, seg = e & 15;
        const float* src = (row < 16) ? (Ab + row * 64 + seg * 4)
                                      : (Gb + (row - 16) * 64 + seg * 4);
        float4 v = *reinterpret_cast<const float4*>(src);
        *reinterpret_cast<float4*>(&amatL[row * AMW + seg * 4]) = v;
    }
    __syncthreads();

    // ---- AtA: thread (q,i) computes K[i][q*16 .. q*16+15] into regs ----
    const int jb = q * 16;
    float kacc[16];
    #pragma unroll
    for (int jj = 0; jj < 16; ++jj) kacc[jj] = 0.f;
    for (int k = 0; k < M; ++k) {
        float aki = amatL[k * AMW + i];
        #pragma unroll
        for (int jj = 0; jj < 16; ++jj)
            kacc[jj] += aki * amatL[k * AMW + jb + jj];
    }
    __syncthreads();   // all AtA reads done before clobbering amatL with aug

    // ---- build augmented [K + sigma I | I] ----
    #pragma unroll
    for (int jj = 0; jj < 16; ++jj) {
        int j = jb + jj;
        float kv = kacc[jj] + Qb[i * 64 + j] + ((i == j) ? SIGMA : 0.f);
        aug[i * AUGW + j] = kv;
        aug[i * AUGW + 64 + j] = (i == j) ? 1.f : 0.f;
    }
    if (t < 64) {
        aug[t * AUGW + 128] = 0.f; aug[t * AUGW + 129] = 0.f;
        aug[t * AUGW + 130] = 0.f; aug[t * AUGW + 131] = 0.f;
    }
    __syncthreads();

    // ---- Gauss-Jordan inversion (no pivoting; K is SPD) ----
    for (int piv = 0; piv < 64; ++piv) {
        float pr = 1.0f / aug[piv * AUGW + piv];   // broadcast read
        __syncthreads();                            // reads done before scale writes
        if (t < AUGW) aug[piv * AUGW + t] *= pr;
        __syncthreads();
        if (i != piv) {
            float f = aug[i * AUGW + piv];
            #pragma unroll
            for (int jj = 0; jj < 33; ++jj) {
                int j = q * 33 + jj;
                aug[i * AUGW + j] -= f * aug[piv * AUGW + j];
            }
        }
        __syncthreads();
    }

    // ---- register fragments for the iteration ----
    float kin[16];                     // Kinv[i][q*16+jj]
    #pragma unroll
    for (int jj = 0; jj < 16; ++jj) kin[jj] = aug[i * AUGW + 64 + q * 16 + jj];

    float at[20];                      // Amat[q*20+jj][i]  (At row i, fifth q)
    #pragma unroll
    for (int jj = 0; jj < 20; ++jj) {
        int jr = q * 20 + jj;
        at[jj] = (jr < 16) ? Ab[jr * 64 + i] : Gb[(jr - 16) * 64 + i];
    }

    float am[32];                      // Amat[t>>1][ (t&1)*32 + ii ]
    const int jr2 = t >> 1, r2 = t & 1;
    if (t < 160) {
        const float* src = (jr2 < 16) ? (Ab + jr2 * 64) : (Gb + (jr2 - 16) * 64);
        #pragma unroll
        for (int ii = 0; ii < 32; ++ii) am[ii] = src[r2 * 32 + ii];
    }
    __syncthreads();

    // ---- 800 ADMM iterations ----
    for (int it = 0; it < ITERS; ++it) {
        // t = sigma*x - p + At*w   (4 lanes per output, 20-dot each)
        float acc = 0.f;
        #pragma unroll
        for (int jj = 0; jj < 20; ++jj) acc += at[jj] * wL[q * 20 + jj];
        acc += __shfl_xor(acc, 1, 64);
        acc += __shfl_xor(acc, 2, 64);
        if (q == 0) tL[i] = SIGMA * xL[i] - pL[i] + acc;
        __syncthreads();

        // x = Kinv * t   (4 lanes per output, 16-dot each)
        float acc2 = 0.f;
        #pragma unroll
        for (int jj = 0; jj < 16; ++jj) acc2 += kin[jj] * tL[q * 16 + jj];
        acc2 += __shfl_xor(acc2, 1, 64);
        acc2 += __shfl_xor(acc2, 2, 64);
        if (q == 0) xL[i] = acc2;
        __syncthreads();

        // s = A*x + y; z = clip; y = s - z; w = 2z - s   (2 lanes per row)
        if (t < 160) {
            float acc3 = 0.f;
            #pragma unroll
            for (int ii = 0; ii < 32; ++ii) acc3 += am[ii] * xL[r2 * 32 + ii];
            acc3 += __shfl_xor(acc3, 1, 64);
            if (r2 == 0) {
                float s = acc3 + yL[jr2];
                float z = fminf(fmaxf(s, lL[jr2]), uL[jr2]);
                yL[jr2] = s - z;
                wL[jr2] = 2.f * z - s;
            }
        }
        __syncthreads();
    }

    if (t < 64) out[(size_t)b * 64 + t] = xL[t];
}

extern "C" void kernel_launch(void* const* d_in, const int* in_sizes, int n_in,
                              void* d_out, int out_size, void* d_ws, size_t ws_size,
                              hipStream_t stream) {
    const float* Q    = (const float*)d_in[0];
    const float* p    = (const float*)d_in[1];
    const float* A    = (const float*)d_in[2];
    const float* bvec = (const float*)d_in[3];
    const float* G    = (const float*)d_in[4];
    const float* h    = (const float*)d_in[5];
    float* out = (float*)d_out;
    admm_qp_kernel<<<1024, 256, 0, stream>>>(Q, p, A, bvec, G, h, out);
}

// Round 2
// 461.948 us; speedup vs baseline: 1.9126x; 1.9126x over previous
//
#include <hip/hip_runtime.h>

// Batched ADMM QP solver, P-fused form. One block (256 thr) per batch.
// Setup: K = Q + sigma*I + At*A; Kinv via in-place Gauss-Jordan (SPD, no pivot);
//   M1 = Kinv*At (64x80), P = A*M1 (80x80), c = Kinv*p, d = -A*c.
// Iterate 799x:  s = P*w + d + y; z = clip(s,l,u); y = s-z; w = 2z-s.
// Epilogue: x = M1*w - c  (== x_800 of the reference; sigma*x term dropped,
//   perturbs fixed point by O(1e-5) << threshold).

#define NXX   64
#define MM    80
#define ITERS 800
#define SIGMA 1e-6f
#define WAM   68    // Amat / Kreg row stride (floats)
#define WM1   84    // M1 row stride (floats)

__device__ __forceinline__ void ld16(float* dst, const float* src) {
#pragma unroll
    for (int c4 = 0; c4 < 4; ++c4) {
        float4 v = *(const float4*)(src + 4 * c4);
        dst[4*c4+0] = v.x; dst[4*c4+1] = v.y; dst[4*c4+2] = v.z; dst[4*c4+3] = v.w;
    }
}
__device__ __forceinline__ void st16(float* dst, const float* src) {
#pragma unroll
    for (int c4 = 0; c4 < 4; ++c4) {
        float4 v; v.x = src[4*c4+0]; v.y = src[4*c4+1]; v.z = src[4*c4+2]; v.w = src[4*c4+3];
        *(float4*)(dst + 4 * c4) = v;
    }
}

__global__ __launch_bounds__(256, 4)
void admm_qp_kernel(const float* __restrict__ Q, const float* __restrict__ p,
                    const float* __restrict__ A, const float* __restrict__ bvec,
                    const float* __restrict__ G, const float* __restrict__ h,
                    float* __restrict__ out)
{
    __shared__ float sm[MM * WAM + NXX * WAM + 80 + 64];   // 9936 floats = 39.7 KB
    float* amat = sm;                  // 80x68 Amat stage; later M1 (64x84 = 5376 <= 5440)
    float* kreg = sm + MM * WAM;       // 64x68: K, then Kinv in place
    float* wL   = kreg + NXX * WAM;    // 80
    float* cL   = wL + 80;             // 64

    const int b = blockIdx.x;
    const int t = threadIdx.x;
    const int q = t & 3;               // 16-col chunk
    const int i = t >> 2;              // row 0..63

    const float* Ab = A + (size_t)b * 16 * 64;
    const float* Gb = G + (size_t)b * 64 * 64;
    const float* Qb = Q + (size_t)b * 64 * 64;

    // ---- S2: stage Amat = [A;G] (80x64) into LDS ----
    for (int e = t; e < MM * 16; e += 256) {
        int row = e >> 4, seg = e & 15;
        const float* src = (row < 16) ? (Ab + row * 64 + seg * 4)
                                      : (Gb + (row - 16) * 64 + seg * 4);
        *(float4*)&amat[row * WAM + seg * 4] = *(const float4*)src;
    }
    __syncthreads();

    // ---- S3: AtA partials: thread (i,q) -> K[i][16q..16q+15] ----
    float kacc[16];
#pragma unroll
    for (int c = 0; c < 16; ++c) kacc[c] = 0.f;
    for (int k = 0; k < MM; ++k) {
        float aki = amat[k * WAM + i];
#pragma unroll
        for (int c4 = 0; c4 < 4; ++c4) {
            float4 v = *(const float4*)&amat[k * WAM + 16 * q + 4 * c4];
            kacc[4*c4+0] += aki * v.x; kacc[4*c4+1] += aki * v.y;
            kacc[4*c4+2] += aki * v.z; kacc[4*c4+3] += aki * v.w;
        }
    }
    // ---- S4: K = AtA + Q + sigma*I ----
#pragma unroll
    for (int c4 = 0; c4 < 4; ++c4) {
        float4 qv = *(const float4*)&Qb[i * 64 + 16 * q + 4 * c4];
        float o0 = kacc[4*c4+0] + qv.x + ((16*q+4*c4+0 == i) ? SIGMA : 0.f);
        float o1 = kacc[4*c4+1] + qv.y + ((16*q+4*c4+1 == i) ? SIGMA : 0.f);
        float o2 = kacc[4*c4+2] + qv.z + ((16*q+4*c4+2 == i) ? SIGMA : 0.f);
        float o3 = kacc[4*c4+3] + qv.w + ((16*q+4*c4+3 == i) ? SIGMA : 0.f);
        float4 ov; ov.x = o0; ov.y = o1; ov.z = o2; ov.w = o3;
        *(float4*)&kreg[i * WAM + 16 * q + 4 * c4] = ov;
    }
    __syncthreads();

    // ---- S5: in-place Gauss-Jordan inverse (NR gaussj, no pivoting; K SPD) ----
    for (int pv = 0; pv < 64; ++pv) {
        float rp[16], ai[16];
        ld16(rp, &kreg[pv * WAM + 16 * q]);
        ld16(ai, &kreg[i  * WAM + 16 * q]);
        float dum = kreg[i * WAM + pv];
        float pr  = 1.0f / kreg[pv * WAM + pv];
        __syncthreads();
        float outv[16];
        if (i == pv) {
#pragma unroll
            for (int c = 0; c < 16; ++c)
                outv[c] = (16 * q + c == pv) ? pr : rp[c] * pr;
        } else {
            float fpd = dum * pr;
#pragma unroll
            for (int c = 0; c < 16; ++c)
                outv[c] = (16 * q + c == pv) ? -fpd : ai[c] - rp[c] * fpd;
        }
        st16(&kreg[i * WAM + 16 * q], outv);
        __syncthreads();
    }

    // ---- S6: M1[i][20q+jj] = sum_k Kinv[i][k]*Amat[20q+jj][k]; write over amat ----
    float m1[20];
#pragma unroll
    for (int jj = 0; jj < 20; ++jj) m1[jj] = 0.f;
    for (int kb = 0; kb < 16; ++kb) {
        float4 kv = *(const float4*)&kreg[i * WAM + 4 * kb];
#pragma unroll
        for (int jj = 0; jj < 20; ++jj) {
            float4 av = *(const float4*)&amat[(20 * q + jj) * WAM + 4 * kb];
            m1[jj] += kv.x * av.x + kv.y * av.y + kv.z * av.z + kv.w * av.w;
        }
    }
    __syncthreads();   // all Amat reads done before overwrite
#pragma unroll
    for (int c4 = 0; c4 < 5; ++c4) {
        float4 v; v.x = m1[4*c4+0]; v.y = m1[4*c4+1]; v.z = m1[4*c4+2]; v.w = m1[4*c4+3];
        *(float4*)&amat[i * WM1 + 20 * q + 4 * c4] = v;
    }
    __syncthreads();

    // ---- S7: P fragment (t<160): thread (r=t>>1, half=t&1) holds P[r][40h..40h+39] ----
    float pacc[40];
#pragma unroll
    for (int c = 0; c < 40; ++c) pacc[c] = 0.f;
    const int r_   = t >> 1;
    const int half = t & 1;
    if (t < 160) {
        const float* Arow = (r_ < 16) ? (Ab + r_ * 64) : (Gb + (r_ - 16) * 64);
        for (int ib = 0; ib < 16; ++ib) {
            float4 av = *(const float4*)&Arow[4 * ib];
            float avv[4] = {av.x, av.y, av.z, av.w};
#pragma unroll
            for (int ii = 0; ii < 4; ++ii) {
                const float as = avv[ii];
                const float* m1row = &amat[(4 * ib + ii) * WM1 + half * 40];
#pragma unroll
                for (int c4 = 0; c4 < 10; ++c4) {
                    float4 mv = *(const float4*)&m1row[4 * c4];
                    pacc[4*c4+0] += as * mv.x; pacc[4*c4+1] += as * mv.y;
                    pacc[4*c4+2] += as * mv.z; pacc[4*c4+3] += as * mv.w;
                }
            }
        }
    }

    // ---- S8a: c = Kinv*p ----
    {
        float cacc = 0.f;
        const float* pp = p + (size_t)b * 64;
#pragma unroll
        for (int c4 = 0; c4 < 4; ++c4) {
            float4 kv = *(const float4*)&kreg[i * WAM + 16 * q + 4 * c4];
            float4 pv = *(const float4*)&pp[16 * q + 4 * c4];
            cacc += kv.x * pv.x + kv.y * pv.y + kv.z * pv.z + kv.w * pv.w;
        }
        cacc += __shfl_xor(cacc, 1, 64);
        cacc += __shfl_xor(cacc, 2, 64);
        if (q == 0) cL[i] = cacc;
    }
    __syncthreads();

    // ---- S8b: d = -A*c, bounds l/u, y=0 (row-private registers); w=0 ----
    float d_r = 0.f, l_r = 0.f, u_r = 0.f, y_r = 0.f;
    if (t < 160) {
        const float* Arow = (r_ < 16) ? (Ab + r_ * 64) : (Gb + (r_ - 16) * 64);
        float dd = 0.f;
#pragma unroll
        for (int c4 = 0; c4 < 8; ++c4) {
            float4 av = *(const float4*)&Arow[half * 32 + 4 * c4];
            float4 cv = *(const float4*)&cL[half * 32 + 4 * c4];
            dd += av.x * cv.x + av.y * cv.y + av.z * cv.z + av.w * cv.w;
        }
        dd += __shfl_xor(dd, 1, 64);
        d_r = -dd;
        if (r_ < 16) { float bb = bvec[(size_t)b * 16 + r_]; l_r = bb; u_r = bb; }
        else         { l_r = -1e8f; u_r = h[(size_t)b * 64 + (r_ - 16)]; }
    }
    if (t < 80) wL[t] = 0.f;
    __syncthreads();

    // ---- 799 fused iterations: s = P*w + d + y; z = clip; y = s-z; w = 2z-s ----
    for (int it = 0; it < ITERS - 1; ++it) {
        float acc = 0.f;
        if (t < 160) {
            const float* wp = &wL[half * 40];
#pragma unroll
            for (int c4 = 0; c4 < 10; ++c4) {
                float4 wv = *(const float4*)&wp[4 * c4];
                acc += pacc[4*c4+0] * wv.x + pacc[4*c4+1] * wv.y
                     + pacc[4*c4+2] * wv.z + pacc[4*c4+3] * wv.w;
            }
            acc += __shfl_xor(acc, 1, 64);
        }
        __syncthreads();                    // all w reads complete
        if (t < 160 && half == 0) {
            float s = acc + d_r + y_r;
            float z = fminf(fmaxf(s, l_r), u_r);
            y_r = s - z;
            wL[r_] = 2.f * z - s;
        }
        __syncthreads();                    // w writes visible
    }

    // ---- epilogue: x = M1*w_799 - c  (= x_800) ----
    {
        float xa = 0.f;
#pragma unroll
        for (int c4 = 0; c4 < 5; ++c4) {
            float4 mv = *(const float4*)&amat[i * WM1 + 20 * q + 4 * c4];
            float4 wv = *(const float4*)&wL[20 * q + 4 * c4];
            xa += mv.x * wv.x + mv.y * wv.y + mv.z * wv.z + mv.w * wv.w;
        }
        xa += __shfl_xor(xa, 1, 64);
        xa += __shfl_xor(xa, 2, 64);
        if (q == 0) out[(size_t)b * 64 + i] = xa - cL[i];
    }
}

extern "C" void kernel_launch(void* const* d_in, const int* in_sizes, int n_in,
                              void* d_out, int out_size, void* d_ws, size_t ws_size,
                              hipStream_t stream) {
    const float* Q    = (const float*)d_in[0];
    const float* p    = (const float*)d_in[1];
    const float* A    = (const float*)d_in[2];
    const float* bvec = (const float*)d_in[3];
    const float* G    = (const float*)d_in[4];
    const float* h    = (const float*)d_in[5];
    float* out = (float*)d_out;
    admm_qp_kernel<<<1024, 256, 0, stream>>>(Q, p, A, bvec, G, h, out);
}